// Round 6
// baseline (1327.224 us; speedup 1.0000x reference)
//
#include <hip/hip_runtime.h>
#include <hip/hip_fp16.h>
#include <stdint.h>

// BiLSTM 2-layer, B=64, T=1024, D=H=128.
// Round 12: round-11's MFMA move worked as predicted (584->471us, MfmaUtil
// 0->23.6, VALUBusy 35->16.5). Remaining step = ~1104 cyc: ~155 MFMA issue +
// ~200-360 VALU issue per SIMD (2 waves serialized) + ~600 serial stall
// (LDS h round-trip, 8-wave barrier skew, dual transcendental chain).
// Restructure: 4 waves x 128 gates/wave (256 thr), 1 wave/SIMD:
//  - same per-SIMD MFMA issue (32 MFMA/step), but VALU contention halves and
//    barrier skew shrinks; __launch_bounds__(256,1) -> 512-VGPR budget for
//    the 128-VGPR weight set (8 nt x 4 kt f16x8).
//  - 2 gates/lane (slots a,b = nt 2q, 2q+1): two independent tail chains
//    interleave (hide each other's latency); xg is one u32/lane.
//  - quad = {i,f,g,o} of TWO adjacent units: h write = 1 ds_write_b32/quad,
//    out store = 1 u32 (hout) or float2 (fout).
// Gate permutation: lane (w,q,ln16): slot s handles unit j=32w+8q+2mq+s,
// gate p=ln16&3 (orig row g = p*128+j). whB row R = w*128+nt*16+c holds
// g = (c&3)*128 + 32w+8(nt>>1)+2(c>>2)+(nt&1). xg PI(g) = 2*tid+s.

#define T_SEQ 1024
#define B_SZ  64
#define M_TOT 65536  // B*T rows

typedef _Float16 h2_t __attribute__((ext_vector_type(2)));
typedef _Float16 f16x8 __attribute__((ext_vector_type(8)));
typedef float f32x4 __attribute__((ext_vector_type(4)));

__device__ inline uint32_t pack2(float a, float b) {
  uint16_t ua = __builtin_bit_cast(uint16_t, (_Float16)a);
  uint16_t ub = __builtin_bit_cast(uint16_t, (_Float16)b);
  return (uint32_t)ua | ((uint32_t)ub << 16);
}

// DPP quad_perm helper (compile-time ctrl). bcast lane q of quad = q*0x55.
template <int CTRL>
__device__ inline float dppf(float v) {
  return __builtin_bit_cast(
      float, __builtin_amdgcn_update_dpp(0, __builtin_bit_cast(int, v), CTRL,
                                         0xF, 0xF, true));
}

// ---------- prep kernels ----------

// Whh [512][128] f32 -> whB rows R = w*128 + nt*16 + c, 64 kw u32 each.
__global__ void prep_whB(const float* __restrict__ Whh, uint32_t* __restrict__ dst) {
  int idx = blockIdx.x * 256 + threadIdx.x;  // < 512*64
  int R = idx >> 6, kw = idx & 63;
  int w = R >> 7, nt = (R >> 4) & 7, cc = R & 15;
  int j = 32 * w + 8 * (nt >> 1) + 2 * (cc >> 2) + (nt & 1);
  int g = (cc & 3) * 128 + j;
  dst[idx] = pack2(Whh[g * 128 + 2 * kw], Whh[g * 128 + 2 * kw + 1]);
}

// Wih [512][2*KW] f32 -> Bt [512 g][KW kw] u32 row-major (= B^T rows for MFMA)
template <int KW>
__global__ void prep_bt(const float* __restrict__ Wih, uint32_t* __restrict__ dst) {
  int idx = blockIdx.x * 256 + threadIdx.x;  // < 512*KW
  constexpr int SH = (KW == 64) ? 6 : 7;
  int g = idx >> SH, kw = idx & (KW - 1);
  dst[idx] = pack2(Wih[g * (2 * KW) + 2 * kw], Wih[g * (2 * KW) + 2 * kw + 1]);
}

__global__ void prep_biasc(const float* __restrict__ bih, const float* __restrict__ bhh,
                           float* __restrict__ dst) {
  int idx = blockIdx.x * 256 + threadIdx.x;  // < 512
  if (idx < 512) dst[idx] = bih[idx] + bhh[idx];
}

// x [B,T,128] f32 -> packed f16x2 [M][64] u32
__global__ void prep_x(const float2* __restrict__ x2, uint32_t* __restrict__ xf16) {
  int idx = blockIdx.x * 256 + threadIdx.x;
  float2 v = x2[idx];
  xf16[idx] = pack2(v.x, v.y);
}

// ---------- xg GEMM: xg[cell][m][512] f16 = A[m][:] . Wih_cell^T + bias ----------
// Store-side permutation PI(g) matches the scan's (w,q,mq,p,s) lane map.
template <int KW>
__global__ __launch_bounds__(256) void xg_gemm(
    const uint32_t* __restrict__ A, const uint32_t* __restrict__ Bt,
    const float* __restrict__ biascat, uint16_t* __restrict__ xg) {
  const int n0 = blockIdx.x * 64;
  const int m0 = blockIdx.y * 64;
  const int tid = threadIdx.x;
  __shared__ uint32_t At[64][36];   // stride 36 words: 16B-aligned quads, 2-way banks
  __shared__ uint32_t Bts[64][36];
  const int lr = tid >> 2, lq = tid & 3;
  const int wave = tid >> 6, lane = tid & 63;
  const int wm = wave >> 1, wn = wave & 1;
  const int q = lane >> 4, ln16 = lane & 15;
  f32x4 acc[2][2] = {};
  for (int kb = 0; kb < KW; kb += 16) {
    uint4 av = *(const uint4*)&A[(size_t)(m0 + lr) * KW + kb + lq * 4];
    uint4 bv = *(const uint4*)&Bt[(size_t)(n0 + lr) * KW + kb + lq * 4];
    __syncthreads();  // previous iteration's fragment reads complete
    *(uint4*)&At[lr][lq * 4] = av;
    *(uint4*)&Bts[lr][lq * 4] = bv;
    __syncthreads();
#pragma unroll
    for (int mi = 0; mi < 2; mi++) {
      f16x8 af = *(const f16x8*)&At[wm * 32 + mi * 16 + ln16][q * 4];
#pragma unroll
      for (int ni = 0; ni < 2; ni++) {
        f16x8 bf = *(const f16x8*)&Bts[wn * 32 + ni * 16 + ln16][q * 4];
        acc[mi][ni] = __builtin_amdgcn_mfma_f32_16x16x32_f16(af, bf, acc[mi][ni], 0, 0, 0);
      }
    }
  }
  // D layout (verified m89/m91): col = lane&15, row = (lane>>4)*4 + reg
#pragma unroll
  for (int mi = 0; mi < 2; mi++)
#pragma unroll
    for (int ni = 0; ni < 2; ni++) {
      int n = n0 + wn * 32 + ni * 16 + ln16;
      int cell = n >> 9, g = n & 511;
      int j = g & 127, pg = g >> 7;
      int PI = ((j >> 5) << 7) | (((j >> 3) & 3) << 5) | (((j >> 1) & 3) << 3) |
               (pg << 1) | (j & 1);
      float bs = biascat[n];
#pragma unroll
      for (int i = 0; i < 4; i++) {
        int m = m0 + wm * 32 + mi * 16 + q * 4 + i;
        float v = acc[mi][ni][i] + bs;
        xg[((size_t)cell * M_TOT + m) * 512 + PI] =
            __builtin_bit_cast(uint16_t, (_Float16)v);
      }
    }
}

// ---------- scan: gates_t = xg_t + Whh.h_{t-1} via MFMA, 4 waves ----------
// 128 WGs (dir*64+b) x 256 thr. Wave w owns gates for units [32w, 32w+32).
// Lane (q=lane>>4, ln16): slot s in {0,1}: z = acc[2q+s][0] is the gate
// p=ln16&3 of unit j=32w+8q+2mq+s. Dual independent tail chains; quad DPP
// broadcast per slot; lane p==0 writes the unit pair (1 u32).
template <bool FINAL>
__global__ __launch_bounds__(256, 1) void scan_kernel(
    const uint16_t* __restrict__ xg, const uint32_t* __restrict__ whB,
    uint32_t* __restrict__ hout, float* __restrict__ fout) {
  const int tid = threadIdx.x;
  const int w = tid >> 6;
  const int lane = tid & 63;
  const int q = lane >> 4;
  const int ln16 = lane & 15;
  const int mq = ln16 >> 2;
  const int p = ln16 & 3;
  const int b = blockIdx.x & 63;
  const int dir = blockIdx.x >> 6;

  __shared__ __align__(16) uint32_t hbuf[2][64];  // [parity][h f16x2]

  // B-fragments: wb[nt][kt]; lane holds whB row (128w+16nt+ln16), k-words
  // [16kt+4q, +4) = 128 VGPRs total.
  f16x8 wb[8][4];
  {
    const uint32_t* wp = whB + (size_t)dir * 512 * 64;
#pragma unroll
    for (int nt = 0; nt < 8; nt++)
#pragma unroll
      for (int kt = 0; kt < 4; kt++)
        wb[nt][kt] = *(const f16x8*)&wp[(128 * w + 16 * nt + ln16) * 64 + 16 * kt + 4 * q];
  }
#pragma unroll
  for (int nt = 0; nt < 8; nt++)
#pragma unroll
    for (int kt = 0; kt < 4; kt++) asm volatile("" : "+v"(wb[nt][kt]));

  // per-lane gate constants: p==2 computes tanh = 2*sigmoid(2z)-1
  const float kmul = (p == 2) ? (-2.0f * 1.44269504f) : -1.44269504f;
  const float gm = (p == 2) ? 2.0f : 1.0f;
  const float gb = (p == 2) ? -1.0f : 0.0f;

  // xg as u32 rows of 256: lane loads its own (slot-a, slot-b) f16 pair.
  const uint32_t* xgp = (const uint32_t*)xg + ((size_t)dir * M_TOT + (size_t)b * T_SEQ) * 256 + tid;

  if (tid < 64) hbuf[0][tid] = 0u;
  float c0 = 0.0f, c1 = 0.0f;
  const f32x4 zero4 = {0.0f, 0.0f, 0.0f, 0.0f};

  // 8-slot prefetch pipeline: slot(s) = s&7; prologue fills steps 0..3.
  uint32_t xr[8];
#pragma unroll
  for (int k = 0; k < 4; k++) {
    const int tk = dir ? (T_SEQ - 1 - k) : k;
    xr[k] = xgp[(size_t)tk * 256];
  }
  __syncthreads();  // prologue: full drain once is fine

  for (int s0 = 0; s0 < T_SEQ; s0 += 8) {
    // re-pin weights each outer iter: forbids spill/remat
#pragma unroll
    for (int nt = 0; nt < 8; nt++)
#pragma unroll
      for (int kt = 0; kt < 4; kt++) asm volatile("" : "+v"(wb[nt][kt]));
#pragma unroll
    for (int k = 0; k < 8; k++) {
      const int s = s0 + k;
      const int par = k & 1;

      // issue prefetch for step s+4 into slot (k+4)&7 (unconditional, clamped)
      {
        int sn = s + 4;
        sn = (sn < T_SEQ) ? sn : (T_SEQ - 1);
        const int tn = dir ? (T_SEQ - 1 - sn) : sn;
        xr[(k + 4) & 7] = xgp[(size_t)tn * 256];
      }

      // MFMA matvec: A rows all identical = h; 8 N-tiles x 4 K-tiles.
      const uint4* hb4 = (const uint4*)&hbuf[par][0];  // 16 x uint4
      f32x4 acc[8];
      {
        f16x8 hk = __builtin_bit_cast(f16x8, hb4[q]);
#pragma unroll
        for (int nt = 0; nt < 8; nt++)
          acc[nt] = __builtin_amdgcn_mfma_f32_16x16x32_f16(hk, wb[nt][0], zero4, 0, 0, 0);
      }
#pragma unroll
      for (int kt = 1; kt < 4; kt++) {
        f16x8 hk = __builtin_bit_cast(f16x8, hb4[kt * 4 + q]);
#pragma unroll
        for (int nt = 0; nt < 8; nt++)
          acc[nt] = __builtin_amdgcn_mfma_f32_16x16x32_f16(hk, wb[nt][kt], acc[nt], 0, 0, 0);
      }

      // lane's two gates: slot s -> acc[2q+s][0] (rows redundant)
      float z0 = (q & 2) ? ((q & 1) ? acc[6][0] : acc[4][0])
                         : ((q & 1) ? acc[2][0] : acc[0][0]);
      float z1 = (q & 2) ? ((q & 1) ? acc[7][0] : acc[5][0])
                         : ((q & 1) ? acc[3][0] : acc[1][0]);

      // fold in xg (counted vmcnt lands here, after the MFMA block)
      h2_t xv = __builtin_bit_cast(h2_t, xr[k]);
      z0 += (float)xv[0];
      z1 += (float)xv[1];

      // dual gate nonlinearities (independent chains interleave)
      float e0 = __builtin_amdgcn_exp2f(z0 * kmul);
      float e1 = __builtin_amdgcn_exp2f(z1 * kmul);
      float sg0 = __builtin_amdgcn_rcpf(1.0f + e0);
      float sg1 = __builtin_amdgcn_rcpf(1.0f + e1);
      float gv0 = __builtin_fmaf(sg0, gm, gb);
      float gv1 = __builtin_fmaf(sg1, gm, gb);

      // quad broadcast per slot: every lane gets i,f,g,o
      float gi0 = dppf<0x00>(gv0), gf0 = dppf<0x55>(gv0);
      float gg0 = dppf<0xAA>(gv0), go0 = dppf<0xFF>(gv0);
      float gi1 = dppf<0x00>(gv1), gf1 = dppf<0x55>(gv1);
      float gg1 = dppf<0xAA>(gv1), go1 = dppf<0xFF>(gv1);

      c0 = __builtin_fmaf(gf0, c0, gi0 * gg0);
      c1 = __builtin_fmaf(gf1, c1, gi1 * gg1);
      float ec0 = __builtin_amdgcn_exp2f(c0 * (-2.0f * 1.44269504f));
      float ec1 = __builtin_amdgcn_exp2f(c1 * (-2.0f * 1.44269504f));
      float th0 = __builtin_fmaf(2.0f, __builtin_amdgcn_rcpf(1.0f + ec0), -1.0f);
      float th1 = __builtin_fmaf(2.0f, __builtin_amdgcn_rcpf(1.0f + ec1), -1.0f);
      float h0 = go0 * th0;
      float h1 = go1 * th1;

      if (p == 0) {
        const int uo = 16 * w + 4 * q + mq;  // unit pair index (j0>>1)
        uint32_t hu = pack2(h0, h1);
        hbuf[par ^ 1][uo] = hu;
        const int t = dir ? (T_SEQ - 1 - s) : s;
        if (FINAL) {
          float2 hv = {h0, h1};
          ((float2*)fout)[(size_t)(b * T_SEQ + t) * 128 + dir * 64 + uo] = hv;
        } else {
          hout[(size_t)(b * T_SEQ + t) * 128 + dir * 64 + uo] = hu;
        }
      }
      // RAW barrier: order ONLY the LDS h-write (lgkmcnt), leave the global
      // prefetch loads / output stores in flight (counted vmcnt at use).
      asm volatile("s_waitcnt lgkmcnt(0)" ::: "memory");
      __builtin_amdgcn_s_barrier();
      asm volatile("" ::: "memory");  // nothing hoists above the barrier
    }
  }
}

extern "C" void kernel_launch(void* const* d_in, const int* in_sizes, int n_in,
                              void* d_out, int out_size, void* d_ws, size_t ws_size,
                              hipStream_t stream) {
  const float* x = (const float*)d_in[0];
  const float* Wih_fw1 = (const float*)d_in[2];
  const float* Whh_fw1 = (const float*)d_in[3];
  const float* bih_fw1 = (const float*)d_in[4];
  const float* bhh_fw1 = (const float*)d_in[5];
  const float* Wih_bw1 = (const float*)d_in[6];
  const float* Whh_bw1 = (const float*)d_in[7];
  const float* bih_bw1 = (const float*)d_in[8];
  const float* bhh_bw1 = (const float*)d_in[9];
  const float* Wih_fw2 = (const float*)d_in[10];
  const float* Whh_fw2 = (const float*)d_in[11];
  const float* bih_fw2 = (const float*)d_in[12];
  const float* bhh_fw2 = (const float*)d_in[13];
  const float* Wih_bw2 = (const float*)d_in[14];
  const float* Whh_bw2 = (const float*)d_in[15];
  const float* bih_bw2 = (const float*)d_in[16];
  const float* bhh_bw2 = (const float*)d_in[17];

  uint8_t* ws = (uint8_t*)d_ws;
  // ws layout (bytes):
  //   0        : whbuf   [4 cells][512 R][64 kw] u32    512 KB
  //   524288   : btbuf1  [2*512][64]  u32               256 KB
  //   786432   : btbuf2  [2*512][128] u32               512 KB
  //   1310720  : biascat [2 layers][1024] f32             8 KB
  //   2097152  : xf16    [M][64] u32                     16 MB
  //   18874368 : out1    [M][128] u32 (f16x2)            32 MB
  //   52428800 : xg      [2][M][512] f16                128 MB
  uint32_t* whbuf = (uint32_t*)(ws + 0);
  uint32_t* btbuf1 = (uint32_t*)(ws + 524288);
  uint32_t* btbuf2 = (uint32_t*)(ws + 786432);
  float* biascat = (float*)(ws + 1310720);
  uint32_t* xf16 = (uint32_t*)(ws + 2097152);
  uint32_t* out1 = (uint32_t*)(ws + 18874368);
  uint16_t* xgbuf = (uint16_t*)(ws + 52428800);
  float* fout = (float*)d_out;

  // --- weight / bias / input packing ---
  prep_whB<<<128, 256, 0, stream>>>(Whh_fw1, whbuf + 0 * 32768);
  prep_whB<<<128, 256, 0, stream>>>(Whh_bw1, whbuf + 1 * 32768);
  prep_whB<<<128, 256, 0, stream>>>(Whh_fw2, whbuf + 2 * 32768);
  prep_whB<<<128, 256, 0, stream>>>(Whh_bw2, whbuf + 3 * 32768);
  prep_bt<64><<<128, 256, 0, stream>>>(Wih_fw1, btbuf1 + 0);
  prep_bt<64><<<128, 256, 0, stream>>>(Wih_bw1, btbuf1 + 512 * 64);
  prep_bt<128><<<256, 256, 0, stream>>>(Wih_fw2, btbuf2 + 0);
  prep_bt<128><<<256, 256, 0, stream>>>(Wih_bw2, btbuf2 + 512 * 128);
  prep_biasc<<<2, 256, 0, stream>>>(bih_fw1, bhh_fw1, biascat + 0);
  prep_biasc<<<2, 256, 0, stream>>>(bih_bw1, bhh_bw1, biascat + 512);
  prep_biasc<<<2, 256, 0, stream>>>(bih_fw2, bhh_fw2, biascat + 1024);
  prep_biasc<<<2, 256, 0, stream>>>(bih_bw2, bhh_bw2, biascat + 1536);
  prep_x<<<(B_SZ * T_SEQ * 64) / 256, 256, 0, stream>>>((const float2*)x, xf16);

  // --- layer 1: xg GEMM + scan ---
  xg_gemm<64><<<dim3(16, 1024), 256, 0, stream>>>(xf16, btbuf1, biascat, xgbuf);
  scan_kernel<false><<<128, 256, 0, stream>>>(xgbuf, whbuf + 0, out1, nullptr);

  // --- layer 2: xg GEMM (reads out1) + scan -> d_out ---
  xg_gemm<128><<<dim3(16, 1024), 256, 0, stream>>>(out1, btbuf2, biascat + 1024, xgbuf);
  scan_kernel<true><<<128, 256, 0, stream>>>(xgbuf, whbuf + 2 * 32768, nullptr, fout);
}